// Round 1
// baseline (199.564 us; speedup 1.0000x reference)
//
#include <hip/hip_runtime.h>

typedef __attribute__((ext_vector_type(8))) short bf16x8;
typedef __attribute__((ext_vector_type(4))) float f32x4;
typedef __attribute__((ext_vector_type(8))) unsigned short u16x8;
typedef __attribute__((ext_vector_type(4))) unsigned short u16x4;

#define NB 8
#define EH 64
#define NS 4096

static __device__ __forceinline__ unsigned short f2bf(float f) {
  union { float f; unsigned int u; } a;
  a.f = f;
  unsigned int u = a.u;
  unsigned int lsb = (u >> 16) & 1u;
  u += 0x7fffu + lsb;  // round-to-nearest-even
  return (unsigned short)(u >> 16);
}

// ---------------- mask dtype detector: 0 = 1-byte bool, 1 = 4-byte (int32 or f32 0/1)
__global__ void k_detect_mask(const unsigned int* __restrict__ M, int* __restrict__ flag) {
  if (threadIdx.x == 0 && blockIdx.x == 0) {
    bool wide = true;
    for (int i = 0; i < 256; ++i) {
      unsigned int w = M[i];
      if (!(w == 0u || w == 1u || w == 0x3F800000u)) { wide = false; break; }
    }
    *flag = wide ? 1 : 0;
  }
}

// ---------------- (B,E,N) f32 -> (B,N,E) bf16 transpose
__global__ __launch_bounds__(256) void k_transpose_bf16(const float* __restrict__ X,
                                                        unsigned short* __restrict__ Y) {
  __shared__ float T[64][69];
  const int b = blockIdx.y;
  const int n0 = blockIdx.x << 6;
  const float* Xb = X + (size_t)b * EH * NS;
  unsigned short* Yb = Y + (size_t)b * NS * EH;
  const int t = threadIdx.x;
  const int er = t >> 4;
  const int n4 = (t & 15) << 2;
#pragma unroll
  for (int p = 0; p < 4; ++p) {
    const int e = er + (p << 4);
    const float4 v = *reinterpret_cast<const float4*>(Xb + (size_t)e * NS + n0 + n4);
    T[e][n4] = v.x; T[e][n4 + 1] = v.y; T[e][n4 + 2] = v.z; T[e][n4 + 3] = v.w;
  }
  __syncthreads();
  const int n = t >> 2;
  const int e0 = (t & 3) << 4;
  u16x8 o0, o1;
#pragma unroll
  for (int j = 0; j < 8; ++j) o0[j] = f2bf(T[e0 + j][n]);
#pragma unroll
  for (int j = 0; j < 8; ++j) o1[j] = f2bf(T[e0 + 8 + j][n]);
  *reinterpret_cast<u16x8*>(Yb + (size_t)(n0 + n) * EH + e0) = o0;
  *reinterpret_cast<u16x8*>(Yb + (size_t)(n0 + n) * EH + e0 + 8) = o1;
}

// ---------------- elementwise f32 -> bf16 (same layout), n = NB*EH*NS
__global__ __launch_bounds__(256) void k_convert_bf16(const float* __restrict__ X,
                                                      unsigned short* __restrict__ Y) {
  const int i = (blockIdx.x * 256 + threadIdx.x) << 2;
  const float4 v = *reinterpret_cast<const float4*>(X + i);
  u16x4 o;
  o[0] = f2bf(v.x); o[1] = f2bf(v.y); o[2] = f2bf(v.z); o[3] = f2bf(v.w);
  *reinterpret_cast<u16x4*>(Y + i) = o;
}

// ---------------- fused flash attention
// Qbf: (B,N,E) bf16, Kbf: (B,N,E) bf16, Vbf: (B,E,N) bf16, mask: (N,N) k-major
__global__ __launch_bounds__(256) void k_attn(const unsigned short* __restrict__ Qbf,
                                              const unsigned short* __restrict__ Kbf,
                                              const unsigned short* __restrict__ Vbf,
                                              const unsigned char* __restrict__ mask8,
                                              const int* __restrict__ mflag_p,
                                              float* __restrict__ Out) {
  __shared__ unsigned short Qs[64][72];
  __shared__ unsigned short Ks[64][72];
  __shared__ unsigned short Vs[64][72];
  __shared__ unsigned char Ms[64][80];
  __shared__ unsigned short Ps[4][16][72];

  const int b = blockIdx.y;
  const int q0 = blockIdx.x << 6;
  const int t = threadIdx.x;
  const int w = t >> 6;
  const int l = t & 63;
  const int l16 = l & 15;
  const int lh = l >> 4;
  const int mflag = *mflag_p;

  // stage Q tile (64 q x 64 e), once
  {
    const unsigned short* src = Qbf + ((size_t)b * NS + q0) * EH;
    const int row = t >> 2, c = (t & 3) << 4;
    *reinterpret_cast<u16x8*>(&Qs[row][c]) = *reinterpret_cast<const u16x8*>(src + row * EH + c);
    *reinterpret_cast<u16x8*>(&Qs[row][c + 8]) = *reinterpret_cast<const u16x8*>(src + row * EH + c + 8);
  }
  __syncthreads();

  bf16x8 aq[2];
  aq[0] = *reinterpret_cast<const bf16x8*>(&Qs[(w << 4) + l16][(lh << 3)]);
  aq[1] = *reinterpret_cast<const bf16x8*>(&Qs[(w << 4) + l16][32 + (lh << 3)]);

  f32x4 acc[4];
  float m_r[4], l_r[4];
#pragma unroll
  for (int i = 0; i < 4; ++i) {
    acc[i] = (f32x4){0.f, 0.f, 0.f, 0.f};
    m_r[i] = -1e30f;
    l_r[i] = 0.f;
  }

  const unsigned short* Ksrc = Kbf + (size_t)b * NS * EH;
  const unsigned short* Vsrc = Vbf + (size_t)b * EH * NS;

  for (int kt = 0; kt < NS / 64; ++kt) {
    const int k0 = kt << 6;
    __syncthreads();  // previous tile fully consumed
    {
      const int row = t >> 2, c = (t & 3) << 4;
      *reinterpret_cast<u16x8*>(&Ks[row][c]) =
          *reinterpret_cast<const u16x8*>(Ksrc + (size_t)(k0 + row) * EH + c);
      *reinterpret_cast<u16x8*>(&Ks[row][c + 8]) =
          *reinterpret_cast<const u16x8*>(Ksrc + (size_t)(k0 + row) * EH + c + 8);
      *reinterpret_cast<u16x8*>(&Vs[row][c]) =
          *reinterpret_cast<const u16x8*>(Vsrc + (size_t)row * NS + k0 + c);
      *reinterpret_cast<u16x8*>(&Vs[row][c + 8]) =
          *reinterpret_cast<const u16x8*>(Vsrc + (size_t)row * NS + k0 + c + 8);
      // mask tile: Ms[k_local][q_local]
      if (mflag == 0) {
        *reinterpret_cast<int4*>(&Ms[row][c]) =
            *reinterpret_cast<const int4*>(mask8 + (size_t)(k0 + row) * NS + q0 + c);
      } else {
        const unsigned int* mw =
            reinterpret_cast<const unsigned int*>(mask8) + (size_t)(k0 + row) * NS + q0 + c;
        unsigned char tmp[16];
#pragma unroll
        for (int j = 0; j < 16; ++j) tmp[j] = (unsigned char)(mw[j] != 0u);
        *reinterpret_cast<int4*>(&Ms[row][c]) = *reinterpret_cast<const int4*>(tmp);
      }
    }
    __syncthreads();

    // S = Q'^T K : D[q][k], contraction over e
    f32x4 sf[4];
#pragma unroll
    for (int kf = 0; kf < 4; ++kf) {
      sf[kf] = (f32x4){0.f, 0.f, 0.f, 0.f};
#pragma unroll
      for (int es = 0; es < 2; ++es) {
        const bf16x8 bk =
            *reinterpret_cast<const bf16x8*>(&Ks[(kf << 4) + l16][(es << 5) + (lh << 3)]);
        sf[kf] = __builtin_amdgcn_mfma_f32_16x16x32_bf16(aq[es], bk, sf[kf], 0, 0, 0);
      }
    }

    // scale + mask; rows q = 4*lh + r (+16w), cols k = 16*kf + l16
    float sc[4][4];
#pragma unroll
    for (int kf = 0; kf < 4; ++kf) {
      const unsigned int mb =
          *reinterpret_cast<const unsigned int*>(&Ms[(kf << 4) + l16][(w << 4) + (lh << 2)]);
#pragma unroll
      for (int r = 0; r < 4; ++r) {
        float v = sf[kf][r] * 0.125f;
        if ((mb >> (r << 3)) & 0xffu) v = -1e30f;
        sc[kf][r] = v;
      }
    }

    // row max over k (4 in-lane cols, then 16 column-lanes)
    float rmax[4];
#pragma unroll
    for (int r = 0; r < 4; ++r)
      rmax[r] = fmaxf(fmaxf(sc[0][r], sc[1][r]), fmaxf(sc[2][r], sc[3][r]));
#pragma unroll
    for (int off = 1; off < 16; off <<= 1) {
#pragma unroll
      for (int r = 0; r < 4; ++r) rmax[r] = fmaxf(rmax[r], __shfl_xor(rmax[r], off, 64));
    }

    // online rescale
#pragma unroll
    for (int r = 0; r < 4; ++r) {
      const float mnew = fmaxf(m_r[r], rmax[r]);
      const float corr = __expf(m_r[r] - mnew);
      m_r[r] = mnew;
      l_r[r] *= corr;
#pragma unroll
      for (int vf = 0; vf < 4; ++vf) acc[vf][r] *= corr;
    }

    // p = exp(s - m); accumulate row sums; write P (bf16) to per-wave LDS
    float rsum[4] = {0.f, 0.f, 0.f, 0.f};
#pragma unroll
    for (int kf = 0; kf < 4; ++kf) {
#pragma unroll
      for (int r = 0; r < 4; ++r) {
        const float p = __expf(sc[kf][r] - m_r[r]);
        rsum[r] += p;
        Ps[w][(lh << 2) + r][(kf << 4) + l16] = f2bf(p);
      }
    }
#pragma unroll
    for (int off = 1; off < 16; off <<= 1) {
#pragma unroll
      for (int r = 0; r < 4; ++r) rsum[r] += __shfl_xor(rsum[r], off, 64);
    }
#pragma unroll
    for (int r = 0; r < 4; ++r) l_r[r] += rsum[r];

    // PV: acc[q][v] += P[q][k] * V'[k][v]
#pragma unroll
    for (int es = 0; es < 2; ++es) {
      const bf16x8 ap = *reinterpret_cast<const bf16x8*>(&Ps[w][l16][(es << 5) + (lh << 3)]);
#pragma unroll
      for (int vf = 0; vf < 4; ++vf) {
        const bf16x8 bv =
            *reinterpret_cast<const bf16x8*>(&Vs[(vf << 4) + l16][(es << 5) + (lh << 3)]);
        acc[vf] = __builtin_amdgcn_mfma_f32_16x16x32_bf16(ap, bv, acc[vf], 0, 0, 0);
      }
    }
  }

  // epilogue: out[b][v][q] = acc / l
  float* outb = Out + (size_t)b * EH * NS;
#pragma unroll
  for (int r = 0; r < 4; ++r) {
    const float inv = 1.0f / l_r[r];
    const int q = q0 + (w << 4) + (lh << 2) + r;
#pragma unroll
    for (int vf = 0; vf < 4; ++vf) {
      const int v = (vf << 4) + l16;
      outb[(size_t)v * NS + q] = acc[vf][r] * inv;
    }
  }
}

extern "C" void kernel_launch(void* const* d_in, const int* in_sizes, int n_in,
                              void* d_out, int out_size, void* d_ws, size_t ws_size,
                              hipStream_t stream) {
  const float* Qf = (const float*)d_in[0];
  const float* Kf = (const float*)d_in[1];
  const float* Vf = (const float*)d_in[2];
  const unsigned char* Mp = (const unsigned char*)d_in[3];
  float* Out = (float*)d_out;

  unsigned short* Qb = (unsigned short*)d_ws;
  unsigned short* Kb = Qb + (size_t)NB * NS * EH;
  unsigned short* Vb = Kb + (size_t)NB * NS * EH;
  int* mflag = (int*)(Vb + (size_t)NB * NS * EH);

  k_detect_mask<<<1, 64, 0, stream>>>((const unsigned int*)Mp, mflag);
  k_transpose_bf16<<<dim3(64, 8), 256, 0, stream>>>(Qf, Qb);
  k_transpose_bf16<<<dim3(64, 8), 256, 0, stream>>>(Kf, Kb);
  k_convert_bf16<<<2048, 256, 0, stream>>>(Vf, Vb);
  k_attn<<<dim3(64, 8), 256, 0, stream>>>(Qb, Kb, Vb, Mp, mflag, Out);
}

// Round 2
// 183.857 us; speedup vs baseline: 1.0854x; 1.0854x over previous
//
#include <hip/hip_runtime.h>

typedef __attribute__((ext_vector_type(8))) short bf16x8;
typedef __attribute__((ext_vector_type(16))) float f32x16;
typedef __attribute__((ext_vector_type(8))) unsigned short u16x8;
typedef __attribute__((ext_vector_type(4))) unsigned short u16x4;
typedef __attribute__((ext_vector_type(4))) unsigned int u32x4;

#define NB 8
#define EH 64
#define NS 4096
#define SCALE_L2E 0.1803368801111204f  /* 0.125 * log2(e) */

static __device__ __forceinline__ unsigned short f2bf(float f) {
  union { float f; unsigned int u; } a;
  a.f = f;
  unsigned int u = a.u;
  unsigned int lsb = (u >> 16) & 1u;
  u += 0x7fffu + lsb;  // RNE
  return (unsigned short)(u >> 16);
}

// pack two f32 -> 2x bf16 (round-half-up, cheap: 4 VALU)
static __device__ __forceinline__ unsigned int pk2(float a, float b) {
  unsigned int ua = __float_as_uint(a) + 0x8000u;
  unsigned int ub = __float_as_uint(b) + 0x8000u;
  return (ua >> 16) | (ub & 0xffff0000u);
}

// ---------------- mask dtype detector: 0 = 1-byte bool, 1 = 4-byte
__global__ void k_detect_mask(const unsigned int* __restrict__ M, int* __restrict__ flag) {
  if (threadIdx.x == 0 && blockIdx.x == 0) {
    bool wide = true;
    for (int i = 0; i < 256; ++i) {
      unsigned int w = M[i];
      if (!(w == 0u || w == 1u || w == 0x3F800000u)) { wide = false; break; }
    }
    *flag = wide ? 1 : 0;
  }
}

// ---------------- mask (Nk,Nq) -> bit-packed transposed (Nq, Nk/64) u64
__global__ __launch_bounds__(256) void k_mask_bits(const unsigned char* __restrict__ M,
                                                   const int* __restrict__ mflag_p,
                                                   unsigned long long* __restrict__ Bits) {
  __shared__ unsigned char Ts[64][80];
  const int q0 = blockIdx.x << 6;
  const int k0 = blockIdx.y << 6;
  const int t = threadIdx.x;
  const int r = t >> 2;   // k-local row
  const int cs = t & 3;   // 16-wide q chunk
  if (*mflag_p == 0) {
    int4 v = *reinterpret_cast<const int4*>(M + (size_t)(k0 + r) * NS + q0 + cs * 16);
    *reinterpret_cast<int4*>(&Ts[r][cs * 16]) = v;
  } else {
    const unsigned int* Mw = reinterpret_cast<const unsigned int*>(M) + (size_t)(k0 + r) * NS + q0 + cs * 16;
    unsigned char tmp[16];
#pragma unroll
    for (int j = 0; j < 16; ++j) tmp[j] = (unsigned char)(Mw[j] != 0u);
    *reinterpret_cast<int4*>(&Ts[r][cs * 16]) = *reinterpret_cast<const int4*>(tmp);
  }
  __syncthreads();
  const int w = t >> 6, lane = t & 63;
#pragma unroll
  for (int i = 0; i < 16; ++i) {
    const int q = (w << 4) + i;
    unsigned long long bm = __ballot(Ts[lane][q] != 0);
    if (lane == 0) Bits[(size_t)(q0 + q) * (NS / 64) + blockIdx.y] = bm;
  }
}

// ---------------- (B,E,N) f32 -> (B,N,E) bf16 transpose (for K)
__global__ __launch_bounds__(256) void k_transpose_bf16(const float* __restrict__ X,
                                                        unsigned short* __restrict__ Y) {
  __shared__ float T[64][69];
  const int b = blockIdx.y;
  const int n0 = blockIdx.x << 6;
  const float* Xb = X + (size_t)b * EH * NS;
  unsigned short* Yb = Y + (size_t)b * NS * EH;
  const int t = threadIdx.x;
  const int er = t >> 4;
  const int n4 = (t & 15) << 2;
#pragma unroll
  for (int p = 0; p < 4; ++p) {
    const int e = er + (p << 4);
    const float4 v = *reinterpret_cast<const float4*>(Xb + (size_t)e * NS + n0 + n4);
    T[e][n4] = v.x; T[e][n4 + 1] = v.y; T[e][n4 + 2] = v.z; T[e][n4 + 3] = v.w;
  }
  __syncthreads();
  const int n = t >> 2;
  const int e0 = (t & 3) << 4;
  u16x8 o0, o1;
#pragma unroll
  for (int j = 0; j < 8; ++j) o0[j] = f2bf(T[e0 + j][n]);
#pragma unroll
  for (int j = 0; j < 8; ++j) o1[j] = f2bf(T[e0 + 8 + j][n]);
  *reinterpret_cast<u16x8*>(Yb + (size_t)(n0 + n) * EH + e0) = o0;
  *reinterpret_cast<u16x8*>(Yb + (size_t)(n0 + n) * EH + e0 + 8) = o1;
}

// ---------------- elementwise f32 -> bf16 (layout preserved; for V)
__global__ __launch_bounds__(256) void k_convert_bf16(const float* __restrict__ X,
                                                      unsigned short* __restrict__ Y) {
  const int i = (blockIdx.x * 256 + threadIdx.x) << 2;
  const float4 v = *reinterpret_cast<const float4*>(X + i);
  u16x4 o;
  o[0] = f2bf(v.x); o[1] = f2bf(v.y); o[2] = f2bf(v.z); o[3] = f2bf(v.w);
  *reinterpret_cast<u16x4*>(Y + i) = o;
}

// ---------------- fused flash attention, swapped operands, LDS-free main loop
// Kb: (B,N,E) bf16; Vb: (B,E,N) bf16; Qf: (B,E,N) f32; Bits: (Nq, Nk/32) u32
__global__ __launch_bounds__(512, 2) void k_attn3(const unsigned short* __restrict__ Kb,
                                                  const unsigned short* __restrict__ Vb,
                                                  const float* __restrict__ Qf,
                                                  const unsigned int* __restrict__ Bits,
                                                  float* __restrict__ Out) {
  __shared__ float SMacc[4][32][66];
  __shared__ float SMml[4][2][64];

  const int b = blockIdx.y;
  const int q0 = blockIdx.x << 7;          // 128 q / block
  const int t = threadIdx.x;
  const int w = t >> 6;
  const int wq = w & 3;                    // q sub-tile (32 rows)
  const int wk = w >> 2;                   // key split (even/odd 32-halves)
  const int l = t & 63;
  const int l32 = l & 31;
  const int hi = l >> 5;

  const int qrow = q0 + (wq << 5) + l32;

  // Q fragments (B operand of S^T = K*Q): 4x bf16x8, scale folded (0.125*log2e)
  bf16x8 qf[4];
  {
    const float* qb = Qf + (size_t)b * EH * NS + qrow;
#pragma unroll
    for (int eb = 0; eb < 4; ++eb) {
#pragma unroll
      for (int j = 0; j < 8; ++j)
        qf[eb][j] = (short)f2bf(qb[(size_t)(16 * eb + 8 * hi + j) * NS] * SCALE_L2E);
    }
  }

  f32x16 acc0, acc1;
#pragma unroll
  for (int r = 0; r < 16; ++r) { acc0[r] = 0.f; acc1[r] = 0.f; }
  float m_r = -1e30f, l_r = 0.f;

  const unsigned short* kp = Kb + ((size_t)b * NS + (wk << 5) + l32) * EH + 8 * hi;
  const unsigned short* vp = Vb + ((size_t)b * EH + l32) * NS + (wk << 5) + 8 * hi;
  const unsigned int* mp = Bits + (size_t)qrow * (NS / 32) + wk;

  for (int kt = 0; kt < NS / 64; ++kt) {
    // ---- loads for this tile (no LDS, no barriers)
    bf16x8 ka[4];
#pragma unroll
    for (int eb = 0; eb < 4; ++eb)
      ka[eb] = *reinterpret_cast<const bf16x8*>(kp + 16 * eb);
    const unsigned int mw = *mp;
    bf16x8 va00 = *reinterpret_cast<const bf16x8*>(vp);                    // kb'=0, vb=0
    bf16x8 va10 = *reinterpret_cast<const bf16x8*>(vp + 16);               // kb'=1, vb=0
    bf16x8 va01 = *reinterpret_cast<const bf16x8*>(vp + (size_t)32 * NS);  // kb'=0, vb=1
    bf16x8 va11 = *reinterpret_cast<const bf16x8*>(vp + (size_t)32 * NS + 16);

    // ---- S^T[k][q] over this wave's 32 keys
    f32x16 s;
#pragma unroll
    for (int r = 0; r < 16; ++r) s[r] = 0.f;
#pragma unroll
    for (int eb = 0; eb < 4; ++eb)
      s = __builtin_amdgcn_mfma_f32_32x32x16_bf16(ka[eb], qf[eb], s, 0, 0, 0);

    // ---- mask (bit k_local of mw), k_local = (r&3) + 8*(r>>2) + 4*hi
#pragma unroll
    for (int r = 0; r < 16; ++r) {
      const int kl = (r & 3) + ((r >> 2) << 3) + (hi << 2);
      s[r] = ((mw >> kl) & 1u) ? -3e30f : s[r];
    }

    // ---- tile max (15 in-lane + 1 cross-half)
    float mx = fmaxf(
        fmaxf(fmaxf(fmaxf(s[0], s[1]), fmaxf(s[2], s[3])), fmaxf(fmaxf(s[4], s[5]), fmaxf(s[6], s[7]))),
        fmaxf(fmaxf(fmaxf(s[8], s[9]), fmaxf(s[10], s[11])), fmaxf(fmaxf(s[12], s[13]), fmaxf(s[14], s[15]))));
    mx = fmaxf(mx, __shfl_xor(mx, 32, 64));

    // ---- online rescale (skipped when max doesn't grow: exact)
    if (!__all(mx <= m_r)) {
      const float mn = fmaxf(m_r, mx);
      const float c = exp2f(m_r - mn);
      m_r = mn;
      l_r *= c;
#pragma unroll
      for (int r = 0; r < 16; ++r) { acc0[r] *= c; acc1[r] *= c; }
    }

    // ---- p = 2^(s - m), tile sum
#pragma unroll
    for (int r = 0; r < 16; ++r) s[r] = exp2f(s[r] - m_r);
    float ts = (((s[0] + s[1]) + (s[2] + s[3])) + ((s[4] + s[5]) + (s[6] + s[7]))) +
               (((s[8] + s[9]) + (s[10] + s[11])) + ((s[12] + s[13]) + (s[14] + s[15])));
    ts += __shfl_xor(ts, 32, 64);
    l_r += ts;

    // ---- pack P to bf16 B-fragments (in-register, lane-pair exchange) + PV
#pragma unroll
    for (int kb = 0; kb < 2; ++kb) {
      const unsigned int wA0 = pk2(s[8 * kb + 0], s[8 * kb + 1]);
      const unsigned int wA1 = pk2(s[8 * kb + 2], s[8 * kb + 3]);
      const unsigned int wB0 = pk2(s[8 * kb + 4], s[8 * kb + 5]);
      const unsigned int wB1 = pk2(s[8 * kb + 6], s[8 * kb + 7]);
      const unsigned int s0 = hi ? wA0 : wB0;
      const unsigned int s1 = hi ? wA1 : wB1;
      const unsigned int r0 = (unsigned int)__shfl_xor((int)s0, 32, 64);
      const unsigned int r1 = (unsigned int)__shfl_xor((int)s1, 32, 64);
      u32x4 pw;
      pw[0] = hi ? r0 : wA0;
      pw[1] = hi ? r1 : wA1;
      pw[2] = hi ? wB0 : r0;
      pw[3] = hi ? wB1 : r1;
      const bf16x8 pfrag = __builtin_bit_cast(bf16x8, pw);
      acc0 = __builtin_amdgcn_mfma_f32_32x32x16_bf16(kb ? va10 : va00, pfrag, acc0, 0, 0, 0);
      acc1 = __builtin_amdgcn_mfma_f32_32x32x16_bf16(kb ? va11 : va01, pfrag, acc1, 0, 0, 0);
    }

    kp += (size_t)64 * EH;  // next 64-key tile
    vp += 64;
    mp += 2;
  }

  // ---- merge the two key-split halves (wk=1 -> LDS -> wk=0), then write O^T
  if (wk == 1) {
#pragma unroll
    for (int r = 0; r < 16; ++r) {
      SMacc[wq][r][l] = acc0[r];
      SMacc[wq][16 + r][l] = acc1[r];
    }
    SMml[wq][0][l] = m_r;
    SMml[wq][1][l] = l_r;
  }
  __syncthreads();
  if (wk == 0) {
    const float m1 = SMml[wq][0][l];
    const float l1 = SMml[wq][1][l];
    const float mxf = fmaxf(m_r, m1);
    float c0 = exp2f(m_r - mxf);
    float c1 = exp2f(m1 - mxf);
    const float inv = 1.0f / (l_r * c0 + l1 * c1);
    c0 *= inv; c1 *= inv;
    float* ob = Out + (size_t)b * EH * NS + q0 + (wq << 5) + l32;
#pragma unroll
    for (int r = 0; r < 16; ++r) {
      const int v0 = (r & 3) + ((r >> 2) << 3) + (hi << 2);
      ob[(size_t)v0 * NS] = acc0[r] * c0 + SMacc[wq][r][l] * c1;
      ob[(size_t)(v0 + 32) * NS] = acc1[r] * c0 + SMacc[wq][16 + r][l] * c1;
    }
  }
}

extern "C" void kernel_launch(void* const* d_in, const int* in_sizes, int n_in,
                              void* d_out, int out_size, void* d_ws, size_t ws_size,
                              hipStream_t stream) {
  const float* Qf = (const float*)d_in[0];
  const float* Kf = (const float*)d_in[1];
  const float* Vf = (const float*)d_in[2];
  const unsigned char* Mp = (const unsigned char*)d_in[3];
  float* Out = (float*)d_out;

  unsigned short* Kb = (unsigned short*)d_ws;                       // 4 MB
  unsigned short* Vb = Kb + (size_t)NB * NS * EH;                   // 4 MB
  unsigned long long* Bits = (unsigned long long*)(Vb + (size_t)NB * NS * EH);  // 2 MB
  int* mflag = (int*)(Bits + (size_t)NS * (NS / 64));

  k_detect_mask<<<1, 64, 0, stream>>>((const unsigned int*)Mp, mflag);
  k_mask_bits<<<dim3(64, 64), 256, 0, stream>>>(Mp, mflag, Bits);
  k_transpose_bf16<<<dim3(64, 8), 256, 0, stream>>>(Kf, Kb);
  k_convert_bf16<<<2048, 256, 0, stream>>>(Vf, Vb);
  k_attn3<<<dim3(32, 8), 512, 0, stream>>>(Kb, Vb, Qf, (const unsigned int*)Bits, Out);
}

// Round 3
// 123.448 us; speedup vs baseline: 1.6166x; 1.4893x over previous
//
#include <hip/hip_runtime.h>

typedef __attribute__((ext_vector_type(8))) short bf16x8;
typedef __attribute__((ext_vector_type(16))) float f32x16;
typedef __attribute__((ext_vector_type(8))) unsigned short u16x8;
typedef __attribute__((ext_vector_type(4))) unsigned short u16x4;
typedef __attribute__((ext_vector_type(4))) unsigned int u32x4;

#define NB 8
#define EH 64
#define NS 4096
#define SCALE_L2E 0.1803368801111204f  /* 0.125 * log2(e) */

static __device__ __forceinline__ unsigned short f2bf(float f) {
  union { float f; unsigned int u; } a;
  a.f = f;
  unsigned int u = a.u;
  unsigned int lsb = (u >> 16) & 1u;
  u += 0x7fffu + lsb;  // RNE
  return (unsigned short)(u >> 16);
}

// pack two f32 -> 2x bf16 (round-half-up)
static __device__ __forceinline__ unsigned int pk2(float a, float b) {
  unsigned int ua = __float_as_uint(a) + 0x8000u;
  unsigned int ub = __float_as_uint(b) + 0x8000u;
  return (ua >> 16) | (ub & 0xffff0000u);
}

// ---------------- mask dtype detector (wave-parallel): 0 = 1-byte bool, 1 = 4-byte
__global__ void k_detect_mask(const unsigned int* __restrict__ M, int* __restrict__ flag) {
  const int l = threadIdx.x;
  bool ok = true;
  for (int i = l; i < 256; i += 64) {
    const unsigned int w = M[i];
    ok = ok && (w == 0u || w == 1u || w == 0x3F800000u);
  }
  const int all_ok = __all(ok) ? 1 : 0;
  if (l == 0) *flag = all_ok;
}

// ---------------- mask (Nk,Nq) -> bit-packed (Nk/32, Nq) u32: Bits[kw32*NS + q]
__global__ __launch_bounds__(256) void k_mask_bits(const unsigned char* __restrict__ M,
                                                   const int* __restrict__ mflag_p,
                                                   unsigned int* __restrict__ Bits) {
  __shared__ unsigned char Ts[64][80];
  const int q0 = blockIdx.x << 6;
  const int k0 = blockIdx.y << 6;
  const int t = threadIdx.x;
  const int r = t >> 2;   // k-local row
  const int cs = t & 3;   // 16-wide q chunk
  if (*mflag_p == 0) {
    int4 v = *reinterpret_cast<const int4*>(M + (size_t)(k0 + r) * NS + q0 + cs * 16);
    *reinterpret_cast<int4*>(&Ts[r][cs * 16]) = v;
  } else {
    const unsigned int* Mw = reinterpret_cast<const unsigned int*>(M) + (size_t)(k0 + r) * NS + q0 + cs * 16;
    unsigned char tmp[16];
#pragma unroll
    for (int j = 0; j < 16; ++j) tmp[j] = (unsigned char)(Mw[j] != 0u);
    *reinterpret_cast<int4*>(&Ts[r][cs * 16]) = *reinterpret_cast<const int4*>(tmp);
  }
  __syncthreads();
  const int w = t >> 6, lane = t & 63;
#pragma unroll
  for (int i = 0; i < 16; ++i) {
    const int q = (w << 4) + i;
    unsigned long long bm = __ballot(Ts[lane][q] != 0);
    if (lane == 0) {
      Bits[(size_t)(2 * blockIdx.y) * NS + q0 + q] = (unsigned int)bm;
      Bits[(size_t)(2 * blockIdx.y + 1) * NS + q0 + q] = (unsigned int)(bm >> 32);
    }
  }
}

// ---------------- fused prepass: z=0 -> K transpose (B,E,N)f32 -> (B,N,E)bf16
//                                 z=1 -> V convert  (B,E,N)f32 -> bf16 same layout
__global__ __launch_bounds__(256) void k_prep(const float* __restrict__ Kf,
                                              const float* __restrict__ Vf,
                                              unsigned short* __restrict__ Kb,
                                              unsigned short* __restrict__ Vb) {
  if (blockIdx.z == 0) {
    __shared__ float T[64][69];
    const int b = blockIdx.y;
    const int n0 = blockIdx.x << 6;
    const float* Xb = Kf + (size_t)b * EH * NS;
    unsigned short* Yb = Kb + (size_t)b * NS * EH;
    const int t = threadIdx.x;
    const int er = t >> 4;
    const int n4 = (t & 15) << 2;
#pragma unroll
    for (int p = 0; p < 4; ++p) {
      const int e = er + (p << 4);
      const float4 v = *reinterpret_cast<const float4*>(Xb + (size_t)e * NS + n0 + n4);
      T[e][n4] = v.x; T[e][n4 + 1] = v.y; T[e][n4 + 2] = v.z; T[e][n4 + 3] = v.w;
    }
    __syncthreads();
    const int n = t >> 2;
    const int e0 = (t & 3) << 4;
    u16x8 o0, o1;
#pragma unroll
    for (int j = 0; j < 8; ++j) o0[j] = f2bf(T[e0 + j][n]);
#pragma unroll
    for (int j = 0; j < 8; ++j) o1[j] = f2bf(T[e0 + 8 + j][n]);
    *reinterpret_cast<u16x8*>(Yb + (size_t)(n0 + n) * EH + e0) = o0;
    *reinterpret_cast<u16x8*>(Yb + (size_t)(n0 + n) * EH + e0 + 8) = o1;
  } else {
    const int id = blockIdx.y * 64 + blockIdx.x;  // 0..511
    const size_t base = (size_t)id * 4096 + threadIdx.x * 4;
#pragma unroll
    for (int i = 0; i < 4; ++i) {
      const float4 v = *reinterpret_cast<const float4*>(Vf + base + i * 1024);
      u16x4 o;
      o[0] = f2bf(v.x); o[1] = f2bf(v.y); o[2] = f2bf(v.z); o[3] = f2bf(v.w);
      *reinterpret_cast<u16x4*>(Vb + base + i * 1024) = o;
    }
  }
}

// ---------------- fused flash attention: LDS-staged supertiles, ksplit=4
// Kb: (B,N,E) bf16; Vb: (B,E,N) bf16; Qf: (B,E,N) f32; Bits: (Nk/32, Nq) u32
__global__ __launch_bounds__(512, 4) void k_attn4(const unsigned short* __restrict__ Kb,
                                                  const unsigned short* __restrict__ Vb,
                                                  const float* __restrict__ Qf,
                                                  const unsigned int* __restrict__ Bits,
                                                  float* __restrict__ Out) {
  // pool: [0,16K) Kt buf0 | [16K,32K) Kt buf1 | [32K,48K) Vt buf0 | [48K,64K) Vt buf1
  // epilogue alias: MAcc [2][3][32][66] f32 (50688 B) | Mml [2][3][2][64] f32 @ 50688
  __shared__ __align__(16) char pool[65536];

  const int bid = blockIdx.x;
  const int b = bid & 7;              // batch -> XCD (L2 locality)
  const int q0 = (bid >> 3) << 6;     // 64 q per block
  const int t = threadIdx.x;
  const int w = t >> 6;
  const int wq = w & 1;               // 2 q sub-tiles of 32
  const int wk = w >> 1;              // 4 key splits
  const int l = t & 63;
  const int l32 = l & 31;
  const int hi = l >> 5;
  const int qrow = q0 + (wq << 5) + l32;

  // ---- Q fragments (B operand of S^T = K*Q), scale folded
  bf16x8 qf[4];
  {
    const float* qb = Qf + (size_t)b * EH * NS + qrow;
#pragma unroll
    for (int eb = 0; eb < 4; ++eb)
#pragma unroll
      for (int j = 0; j < 8; ++j)
        qf[eb][j] = (short)f2bf(qb[(size_t)(16 * eb + 8 * hi + j) * NS] * SCALE_L2E);
  }

  // ---- staging addressing (sources linear/coalesced; swizzle on LDS dest)
  const char* ksrc = (const char*)(Kb + (size_t)b * NS * EH) + (size_t)t * 16;
  const int vrow = t >> 4, vslot = t & 15;
  const char* vsrc = (const char*)(Vb + (size_t)b * EH * NS) + (size_t)vrow * (NS * 2) + (size_t)vslot * 16;
  const int krow = t >> 3;
  const int kd0 = (krow << 7) + (((t & 7) << 4) ^ ((krow & 7) << 4));
  const int kd1 = kd0 + 8192;  // +64 rows: row&7 unchanged
  const int vd0 = (vrow << 8) + ((vslot << 4) ^ ((vrow & 15) << 4));
  const int vd1 = vd0 + 8192;  // +32 rows: row&15 unchanged

  // ---- LDS read offsets (same XOR as write side)
  const int R = (wk << 5) + l32;  // key row in supertile
  int koff[4];
#pragma unroll
  for (int eb = 0; eb < 4; ++eb)
    koff[eb] = (R << 7) + (((eb << 5) + (hi << 4)) ^ ((R & 7) << 4));
  int voff[2][2];
#pragma unroll
  for (int vb = 0; vb < 2; ++vb)
#pragma unroll
    for (int kb = 0; kb < 2; ++kb) {
      const int e = (vb << 5) + l32;
      voff[vb][kb] = (e << 8) + (((wk << 6) + (kb << 5) + (hi << 4)) ^ ((e & 15) << 4));
    }

  const unsigned int* mp = Bits + (size_t)wk * NS + qrow;  // word (kt*4+wk)

  f32x16 acc0, acc1;
#pragma unroll
  for (int r = 0; r < 16; ++r) { acc0[r] = 0.f; acc1[r] = 0.f; }
  float m_r = -1e30f, l_r = 0.f;

  // ---- prologue: stage supertile 0
  uint4 rk0 = *reinterpret_cast<const uint4*>(ksrc);
  uint4 rk1 = *reinterpret_cast<const uint4*>(ksrc + 8192);
  uint4 rv0 = *reinterpret_cast<const uint4*>(vsrc);
  uint4 rv1 = *reinterpret_cast<const uint4*>(vsrc + (size_t)32 * NS * 2);
  unsigned int mw = mp[0];
  *reinterpret_cast<uint4*>(pool + kd0) = rk0;
  *reinterpret_cast<uint4*>(pool + kd1) = rk1;
  *reinterpret_cast<uint4*>(pool + 32768 + vd0) = rv0;
  *reinterpret_cast<uint4*>(pool + 32768 + vd1) = rv1;
  __syncthreads();

  unsigned int mw_n = 0;
  for (int kt = 0; kt < 32; ++kt) {
    const int cur = kt & 1;
    // T14: issue next-tile global loads early (latency hides under compute)
    if (kt < 31) {
      const size_t ko = (size_t)(kt + 1) * 16384;
      rk0 = *reinterpret_cast<const uint4*>(ksrc + ko);
      rk1 = *reinterpret_cast<const uint4*>(ksrc + ko + 8192);
      const size_t vo = (size_t)(kt + 1) * 256;
      rv0 = *reinterpret_cast<const uint4*>(vsrc + vo);
      rv1 = *reinterpret_cast<const uint4*>(vsrc + vo + (size_t)32 * NS * 2);
      mw_n = mp[(size_t)(kt + 1) * 4 * NS];
    }

    const char* Kt = pool + cur * 16384;
    const char* Vt = pool + 32768 + cur * 16384;

    // ---- S^T[k][q]
    bf16x8 ka0 = *reinterpret_cast<const bf16x8*>(Kt + koff[0]);
    bf16x8 ka1 = *reinterpret_cast<const bf16x8*>(Kt + koff[1]);
    bf16x8 ka2 = *reinterpret_cast<const bf16x8*>(Kt + koff[2]);
    bf16x8 ka3 = *reinterpret_cast<const bf16x8*>(Kt + koff[3]);
    f32x16 s;
#pragma unroll
    for (int r = 0; r < 16; ++r) s[r] = 0.f;
    s = __builtin_amdgcn_mfma_f32_32x32x16_bf16(ka0, qf[0], s, 0, 0, 0);
    s = __builtin_amdgcn_mfma_f32_32x32x16_bf16(ka1, qf[1], s, 0, 0, 0);
    s = __builtin_amdgcn_mfma_f32_32x32x16_bf16(ka2, qf[2], s, 0, 0, 0);
    s = __builtin_amdgcn_mfma_f32_32x32x16_bf16(ka3, qf[3], s, 0, 0, 0);

    // ---- mask: bit k_local of mw, k_local = (r&3) + 8*(r>>2) + 4*hi
#pragma unroll
    for (int r = 0; r < 16; ++r) {
      const int kl = (r & 3) + ((r >> 2) << 3) + (hi << 2);
      s[r] = ((mw >> kl) & 1u) ? -3e30f : s[r];
    }

    // ---- tile max
    float mx = fmaxf(
        fmaxf(fmaxf(fmaxf(s[0], s[1]), fmaxf(s[2], s[3])), fmaxf(fmaxf(s[4], s[5]), fmaxf(s[6], s[7]))),
        fmaxf(fmaxf(fmaxf(s[8], s[9]), fmaxf(s[10], s[11])), fmaxf(fmaxf(s[12], s[13]), fmaxf(s[14], s[15]))));
    mx = fmaxf(mx, __shfl_xor(mx, 32, 64));

    // ---- online rescale (skip when max doesn't grow: exact)
    if (!__all(mx <= m_r)) {
      const float mn = fmaxf(m_r, mx);
      const float c = exp2f(m_r - mn);
      m_r = mn;
      l_r *= c;
#pragma unroll
      for (int r = 0; r < 16; ++r) { acc0[r] *= c; acc1[r] *= c; }
    }

    // ---- p = 2^(s-m), tile sum
#pragma unroll
    for (int r = 0; r < 16; ++r) s[r] = exp2f(s[r] - m_r);
    float ts = (((s[0] + s[1]) + (s[2] + s[3])) + ((s[4] + s[5]) + (s[6] + s[7]))) +
               (((s[8] + s[9]) + (s[10] + s[11])) + ((s[12] + s[13]) + (s[14] + s[15])));
    ts += __shfl_xor(ts, 32, 64);
    l_r += ts;

    // ---- PV (in-register P pack, lane-half exchange)
    bf16x8 va00 = *reinterpret_cast<const bf16x8*>(Vt + voff[0][0]);
    bf16x8 va01 = *reinterpret_cast<const bf16x8*>(Vt + voff[1][0]);
    bf16x8 va10 = *reinterpret_cast<const bf16x8*>(Vt + voff[0][1]);
    bf16x8 va11 = *reinterpret_cast<const bf16x8*>(Vt + voff[1][1]);
#pragma unroll
    for (int kb = 0; kb < 2; ++kb) {
      const unsigned int wA0 = pk2(s[8 * kb + 0], s[8 * kb + 1]);
      const unsigned int wA1 = pk2(s[8 * kb + 2], s[8 * kb + 3]);
      const unsigned int wB0 = pk2(s[8 * kb + 4], s[8 * kb + 5]);
      const unsigned int wB1 = pk2(s[8 * kb + 6], s[8 * kb + 7]);
      const unsigned int s0 = hi ? wA0 : wB0;
      const unsigned int s1 = hi ? wA1 : wB1;
      const unsigned int r0 = (unsigned int)__shfl_xor((int)s0, 32, 64);
      const unsigned int r1 = (unsigned int)__shfl_xor((int)s1, 32, 64);
      u32x4 pw;
      pw[0] = hi ? r0 : wA0;
      pw[1] = hi ? r1 : wA1;
      pw[2] = hi ? wB0 : r0;
      pw[3] = hi ? wB1 : r1;
      const bf16x8 pfrag = __builtin_bit_cast(bf16x8, pw);
      acc0 = __builtin_amdgcn_mfma_f32_32x32x16_bf16(kb ? va10 : va00, pfrag, acc0, 0, 0, 0);
      acc1 = __builtin_amdgcn_mfma_f32_32x32x16_bf16(kb ? va11 : va01, pfrag, acc1, 0, 0, 0);
    }

    // T14: write staged regs to the other buffer (vmcnt wait lands here)
    if (kt < 31) {
      char* Ktn = pool + (cur ^ 1) * 16384;
      char* Vtn = pool + 32768 + (cur ^ 1) * 16384;
      *reinterpret_cast<uint4*>(Ktn + kd0) = rk0;
      *reinterpret_cast<uint4*>(Ktn + kd1) = rk1;
      *reinterpret_cast<uint4*>(Vtn + vd0) = rv0;
      *reinterpret_cast<uint4*>(Vtn + vd1) = rv1;
      mw = mw_n;
    }
    __syncthreads();
  }

  // ---- 4-way merge through LDS (aliases staging pool; loop's last barrier guards)
  float* MAcc = reinterpret_cast<float*>(pool);            // [2][3][32][66]
  float* Mml = reinterpret_cast<float*>(pool + 50688);     // [2][3][2][64]
  if (wk > 0) {
    float* A = MAcc + (size_t)(wq * 3 + (wk - 1)) * 32 * 66;
#pragma unroll
    for (int r = 0; r < 16; ++r) {
      A[r * 66 + l] = acc0[r];
      A[(16 + r) * 66 + l] = acc1[r];
    }
    float* Mm = Mml + (wq * 3 + (wk - 1)) * 128;
    Mm[l] = m_r;
    Mm[64 + l] = l_r;
  }
  __syncthreads();
  if (wk == 0) {
    float M = m_r;
#pragma unroll
    for (int s0 = 0; s0 < 3; ++s0) M = fmaxf(M, Mml[(wq * 3 + s0) * 128 + l]);
    const float c_self = exp2f(m_r - M);
    float cs[3];
    float L = l_r * c_self;
#pragma unroll
    for (int s0 = 0; s0 < 3; ++s0) {
      cs[s0] = exp2f(Mml[(wq * 3 + s0) * 128 + l] - M);
      L += Mml[(wq * 3 + s0) * 128 + 64 + l] * cs[s0];
    }
    const float inv = 1.0f / L;
    float* ob = Out + (size_t)b * EH * NS + qrow;
#pragma unroll
    for (int r = 0; r < 16; ++r) {
      const int v0 = (r & 3) + ((r >> 2) << 3) + (hi << 2);
      float o0 = acc0[r] * c_self;
      float o1 = acc1[r] * c_self;
#pragma unroll
      for (int s0 = 0; s0 < 3; ++s0) {
        const float* A = MAcc + (size_t)(wq * 3 + s0) * 32 * 66;
        o0 += A[r * 66 + l] * cs[s0];
        o1 += A[(16 + r) * 66 + l] * cs[s0];
      }
      ob[(size_t)v0 * NS] = o0 * inv;
      ob[(size_t)(v0 + 32) * NS] = o1 * inv;
    }
  }
}

extern "C" void kernel_launch(void* const* d_in, const int* in_sizes, int n_in,
                              void* d_out, int out_size, void* d_ws, size_t ws_size,
                              hipStream_t stream) {
  const float* Qf = (const float*)d_in[0];
  const float* Kf = (const float*)d_in[1];
  const float* Vf = (const float*)d_in[2];
  const unsigned char* Mp = (const unsigned char*)d_in[3];
  float* Out = (float*)d_out;

  unsigned short* Kb = (unsigned short*)d_ws;                       // 4 MB
  unsigned short* Vb = Kb + (size_t)NB * NS * EH;                   // 4 MB
  unsigned int* Bits = (unsigned int*)(Vb + (size_t)NB * NS * EH);  // 2 MB
  int* mflag = (int*)(Bits + (size_t)NS * (NS / 32));

  k_detect_mask<<<1, 64, 0, stream>>>((const unsigned int*)Mp, mflag);
  k_mask_bits<<<dim3(64, 64), 256, 0, stream>>>(Mp, mflag, Bits);
  k_prep<<<dim3(64, 8, 2), 256, 0, stream>>>(Kf, Vf, Kb, Vb);
  k_attn4<<<dim3(512), 512, 0, stream>>>(Kb, Vb, Qf, Bits, Out);
}

// Round 4
// 119.899 us; speedup vs baseline: 1.6644x; 1.0296x over previous
//
#include <hip/hip_runtime.h>

typedef __attribute__((ext_vector_type(8))) short bf16x8;
typedef __attribute__((ext_vector_type(16))) float f32x16;
typedef __attribute__((ext_vector_type(8))) unsigned short u16x8;
typedef __attribute__((ext_vector_type(4))) unsigned short u16x4;
typedef __attribute__((ext_vector_type(4))) unsigned int u32x4;
typedef __attribute__((ext_vector_type(2))) unsigned int u32x2;

#define NB 8
#define EH 64
#define NS 4096
#define SCALE_L2E 0.1803368801111204f  /* 0.125 * log2(e) */

static __device__ __forceinline__ unsigned short f2bf(float f) {
  union { float f; unsigned int u; } a;
  a.f = f;
  unsigned int u = a.u;
  unsigned int lsb = (u >> 16) & 1u;
  u += 0x7fffu + lsb;  // RNE
  return (unsigned short)(u >> 16);
}

// v_cvt_pk_bf16_f32: dst.lo16 = bf16(a), dst.hi16 = bf16(b) -- 1 VALU op
static __device__ __forceinline__ unsigned int cvtpk(float a, float b) {
  unsigned int r;
  asm("v_cvt_pk_bf16_f32 %0, %1, %2" : "=v"(r) : "v"(a), "v"(b));
  return r;
}

// cross-half (lane ^ 32) reduce via v_permlane32_swap (VALU, no LDS crossbar)
static __device__ __forceinline__ float xmax32(float x) {
  u32x2 r = __builtin_amdgcn_permlane32_swap(__float_as_uint(x), __float_as_uint(x), false, false);
  return fmaxf(__uint_as_float(r[0]), __uint_as_float(r[1]));
}
static __device__ __forceinline__ float xsum32(float x) {
  u32x2 r = __builtin_amdgcn_permlane32_swap(__float_as_uint(x), __float_as_uint(x), false, false);
  return __uint_as_float(r[0]) + __uint_as_float(r[1]);
}

// ---------------- mask dtype detector (wave-parallel): 0 = 1-byte bool, 1 = 4-byte
__global__ void k_detect_mask(const unsigned int* __restrict__ M, int* __restrict__ flag) {
  const int l = threadIdx.x;
  bool ok = true;
  for (int i = l; i < 256; i += 64) {
    const unsigned int w = M[i];
    ok = ok && (w == 0u || w == 1u || w == 0x3F800000u);
  }
  const int all_ok = __all(ok) ? 1 : 0;
  if (l == 0) *flag = all_ok;
}

// ---------------- mask (Nk,Nq) -> bit-packed (Nk/32, Nq) u32: Bits[kw32*NS + q]
__global__ __launch_bounds__(256) void k_mask_bits(const unsigned char* __restrict__ M,
                                                   const int* __restrict__ mflag_p,
                                                   unsigned int* __restrict__ Bits) {
  __shared__ unsigned char Ts[64][80];
  const int q0 = blockIdx.x << 6;
  const int k0 = blockIdx.y << 6;
  const int t = threadIdx.x;
  const int r = t >> 2;   // k-local row
  const int cs = t & 3;   // 16-wide q chunk
  if (*mflag_p == 0) {
    int4 v = *reinterpret_cast<const int4*>(M + (size_t)(k0 + r) * NS + q0 + cs * 16);
    *reinterpret_cast<int4*>(&Ts[r][cs * 16]) = v;
  } else {
    const unsigned int* Mw = reinterpret_cast<const unsigned int*>(M) + (size_t)(k0 + r) * NS + q0 + cs * 16;
    unsigned char tmp[16];
#pragma unroll
    for (int j = 0; j < 16; ++j) tmp[j] = (unsigned char)(Mw[j] != 0u);
    *reinterpret_cast<int4*>(&Ts[r][cs * 16]) = *reinterpret_cast<const int4*>(tmp);
  }
  __syncthreads();
  const int w = t >> 6, lane = t & 63;
#pragma unroll
  for (int i = 0; i < 16; ++i) {
    const int q = (w << 4) + i;
    unsigned long long bm = __ballot(Ts[lane][q] != 0);
    if (lane == 0) {
      Bits[(size_t)(2 * blockIdx.y) * NS + q0 + q] = (unsigned int)bm;
      Bits[(size_t)(2 * blockIdx.y + 1) * NS + q0 + q] = (unsigned int)(bm >> 32);
    }
  }
}

// ---------------- fused prepass: z=0 -> K transpose (B,E,N)f32 -> (B,N,E)bf16
//                                 z=1 -> V convert  (B,E,N)f32 -> bf16 same layout
__global__ __launch_bounds__(256) void k_prep(const float* __restrict__ Kf,
                                              const float* __restrict__ Vf,
                                              unsigned short* __restrict__ Kb,
                                              unsigned short* __restrict__ Vb) {
  if (blockIdx.z == 0) {
    __shared__ float T[64][69];
    const int b = blockIdx.y;
    const int n0 = blockIdx.x << 6;
    const float* Xb = Kf + (size_t)b * EH * NS;
    unsigned short* Yb = Kb + (size_t)b * NS * EH;
    const int t = threadIdx.x;
    const int er = t >> 4;
    const int n4 = (t & 15) << 2;
#pragma unroll
    for (int p = 0; p < 4; ++p) {
      const int e = er + (p << 4);
      const float4 v = *reinterpret_cast<const float4*>(Xb + (size_t)e * NS + n0 + n4);
      T[e][n4] = v.x; T[e][n4 + 1] = v.y; T[e][n4 + 2] = v.z; T[e][n4 + 3] = v.w;
    }
    __syncthreads();
    const int n = t >> 2;
    const int e0 = (t & 3) << 4;
    u16x8 o0, o1;
#pragma unroll
    for (int j = 0; j < 8; ++j) o0[j] = f2bf(T[e0 + j][n]);
#pragma unroll
    for (int j = 0; j < 8; ++j) o1[j] = f2bf(T[e0 + 8 + j][n]);
    *reinterpret_cast<u16x8*>(Yb + (size_t)(n0 + n) * EH + e0) = o0;
    *reinterpret_cast<u16x8*>(Yb + (size_t)(n0 + n) * EH + e0 + 8) = o1;
  } else {
    const int id = blockIdx.y * 64 + blockIdx.x;  // 0..511
    const size_t base = (size_t)id * 4096 + threadIdx.x * 4;
#pragma unroll
    for (int i = 0; i < 4; ++i) {
      const float4 v = *reinterpret_cast<const float4*>(Vf + base + i * 1024);
      u16x4 o;
      o[0] = f2bf(v.x); o[1] = f2bf(v.y); o[2] = f2bf(v.z); o[3] = f2bf(v.w);
      *reinterpret_cast<u16x4*>(Vb + base + i * 1024) = o;
    }
  }
}

// ---------------- fused flash attention: LDS-staged supertiles, ksplit=4
// Kb: (B,N,E) bf16; Vb: (B,E,N) bf16; Qf: (B,E,N) f32; Bits: (Nk/32, Nq) u32
__global__ __launch_bounds__(512, 4) void k_attn4(const unsigned short* __restrict__ Kb,
                                                  const unsigned short* __restrict__ Vb,
                                                  const float* __restrict__ Qf,
                                                  const unsigned int* __restrict__ Bits,
                                                  float* __restrict__ Out) {
  // pool: [0,16K) Kt buf0 | [16K,32K) Kt buf1 | [32K,48K) Vt buf0 | [48K,64K) Vt buf1
  // epilogue alias: MAcc [2][3][32][66] f32 (50688 B) | Mml [2][3][2][64] f32 @ 50688
  __shared__ __align__(16) char pool[65536];

  const int bid = blockIdx.x;
  const int b = bid & 7;              // batch -> XCD (L2 locality)
  const int q0 = (bid >> 3) << 6;     // 64 q per block
  const int t = threadIdx.x;
  const int w = t >> 6;
  const int wq = w & 1;               // 2 q sub-tiles of 32
  const int wk = w >> 1;              // 4 key splits
  const int l = t & 63;
  const int l32 = l & 31;
  const int hi = l >> 5;
  const int qrow = q0 + (wq << 5) + l32;

  // ---- Q fragments (B operand of S^T = K*Q), scale folded
  bf16x8 qf[4];
  {
    const float* qb = Qf + (size_t)b * EH * NS + qrow;
#pragma unroll
    for (int eb = 0; eb < 4; ++eb)
#pragma unroll
      for (int j = 0; j < 8; ++j)
        qf[eb][j] = (short)f2bf(qb[(size_t)(16 * eb + 8 * hi + j) * NS] * SCALE_L2E);
  }

  // ---- staging addressing (sources linear/coalesced; swizzle on LDS dest)
  const char* ksrc = (const char*)(Kb + (size_t)b * NS * EH) + (size_t)t * 16;
  const int vrow = t >> 4, vslot = t & 15;
  const char* vsrc = (const char*)(Vb + (size_t)b * EH * NS) + (size_t)vrow * (NS * 2) + (size_t)vslot * 16;
  const int krow = t >> 3;
  const int kd0 = (krow << 7) + (((t & 7) << 4) ^ ((krow & 7) << 4));
  const int kd1 = kd0 + 8192;  // +64 rows: row&7 unchanged
  const int vd0 = (vrow << 8) + ((vslot << 4) ^ ((vrow & 15) << 4));
  const int vd1 = vd0 + 8192;  // +32 rows: row&15 unchanged

  // ---- LDS read offsets (same XOR as write side)
  const int R = (wk << 5) + l32;  // key row in supertile
  int koff[4];
#pragma unroll
  for (int eb = 0; eb < 4; ++eb)
    koff[eb] = (R << 7) + (((eb << 5) + (hi << 4)) ^ ((R & 7) << 4));
  int voff[2][2];
#pragma unroll
  for (int vb = 0; vb < 2; ++vb)
#pragma unroll
    for (int kb = 0; kb < 2; ++kb) {
      const int e = (vb << 5) + l32;
      voff[vb][kb] = (e << 8) + (((wk << 6) + (kb << 5) + (hi << 4)) ^ ((e & 15) << 4));
    }

  const unsigned int* mp = Bits + (size_t)wk * NS + qrow;  // word (kt*4+wk)

  f32x16 acc0, acc1;
#pragma unroll
  for (int r = 0; r < 16; ++r) { acc0[r] = 0.f; acc1[r] = 0.f; }
  float m_r = -1e30f, l_r = 0.f;

  // ---- prologue: stage supertile 0
  uint4 rk0 = *reinterpret_cast<const uint4*>(ksrc);
  uint4 rk1 = *reinterpret_cast<const uint4*>(ksrc + 8192);
  uint4 rv0 = *reinterpret_cast<const uint4*>(vsrc);
  uint4 rv1 = *reinterpret_cast<const uint4*>(vsrc + (size_t)32 * NS * 2);
  unsigned int mw = mp[0];
  *reinterpret_cast<uint4*>(pool + kd0) = rk0;
  *reinterpret_cast<uint4*>(pool + kd1) = rk1;
  *reinterpret_cast<uint4*>(pool + 32768 + vd0) = rv0;
  *reinterpret_cast<uint4*>(pool + 32768 + vd1) = rv1;
  __syncthreads();

  unsigned int mw_n = 0;
  for (int kt = 0; kt < 32; ++kt) {
    const int cur = kt & 1;
    // T14: issue next-tile global loads early (latency hides under compute)
    if (kt < 31) {
      const size_t ko = (size_t)(kt + 1) * 16384;
      rk0 = *reinterpret_cast<const uint4*>(ksrc + ko);
      rk1 = *reinterpret_cast<const uint4*>(ksrc + ko + 8192);
      const size_t vo = (size_t)(kt + 1) * 256;
      rv0 = *reinterpret_cast<const uint4*>(vsrc + vo);
      rv1 = *reinterpret_cast<const uint4*>(vsrc + vo + (size_t)32 * NS * 2);
      mw_n = mp[(size_t)(kt + 1) * 4 * NS];
    }

    const char* Kt = pool + cur * 16384;
    const char* Vt = pool + 32768 + cur * 16384;

    // ---- S^T init = mask (C-operand trick): masked entries start at -3e30
    f32x16 s;
#pragma unroll
    for (int r = 0; r < 16; ++r) {
      const int kl = (r & 3) + ((r >> 2) << 3) + (hi << 2);
      s[r] = ((mw >> kl) & 1u) ? -3e30f : 0.0f;
    }

    // ---- S^T[k][q]
    bf16x8 ka0 = *reinterpret_cast<const bf16x8*>(Kt + koff[0]);
    bf16x8 ka1 = *reinterpret_cast<const bf16x8*>(Kt + koff[1]);
    bf16x8 ka2 = *reinterpret_cast<const bf16x8*>(Kt + koff[2]);
    bf16x8 ka3 = *reinterpret_cast<const bf16x8*>(Kt + koff[3]);
    __builtin_amdgcn_s_setprio(1);
    s = __builtin_amdgcn_mfma_f32_32x32x16_bf16(ka0, qf[0], s, 0, 0, 0);
    s = __builtin_amdgcn_mfma_f32_32x32x16_bf16(ka1, qf[1], s, 0, 0, 0);
    s = __builtin_amdgcn_mfma_f32_32x32x16_bf16(ka2, qf[2], s, 0, 0, 0);
    s = __builtin_amdgcn_mfma_f32_32x32x16_bf16(ka3, qf[3], s, 0, 0, 0);
    __builtin_amdgcn_s_setprio(0);

    // ---- tile max (15 in-lane + 1 permlane cross-half)
    float mx = fmaxf(
        fmaxf(fmaxf(fmaxf(s[0], s[1]), fmaxf(s[2], s[3])), fmaxf(fmaxf(s[4], s[5]), fmaxf(s[6], s[7]))),
        fmaxf(fmaxf(fmaxf(s[8], s[9]), fmaxf(s[10], s[11])), fmaxf(fmaxf(s[12], s[13]), fmaxf(s[14], s[15]))));
    mx = xmax32(mx);

    // ---- deferred online rescale (T13, THR=8: p bounded by 2^8, exact normalize later)
    if (!__all(mx <= m_r + 8.0f)) {
      const float mn = fmaxf(m_r, mx);
      const float c = exp2f(m_r - mn);
      m_r = mn;
      l_r *= c;
#pragma unroll
      for (int r = 0; r < 16; ++r) { acc0[r] *= c; acc1[r] *= c; }
    }

    // ---- p = 2^(s-m), tile sum
#pragma unroll
    for (int r = 0; r < 16; ++r) s[r] = exp2f(s[r] - m_r);
    float ts = (((s[0] + s[1]) + (s[2] + s[3])) + ((s[4] + s[5]) + (s[6] + s[7]))) +
               (((s[8] + s[9]) + (s[10] + s[11])) + ((s[12] + s[13]) + (s[14] + s[15])));
    l_r += xsum32(ts);

    // ---- PV: cvt_pk -> permlane32_swap -> 2 MFMAs per 16-key group (T12)
    bf16x8 va00 = *reinterpret_cast<const bf16x8*>(Vt + voff[0][0]);
    bf16x8 va01 = *reinterpret_cast<const bf16x8*>(Vt + voff[1][0]);
    bf16x8 va10 = *reinterpret_cast<const bf16x8*>(Vt + voff[0][1]);
    bf16x8 va11 = *reinterpret_cast<const bf16x8*>(Vt + voff[1][1]);
#pragma unroll
    for (int kb = 0; kb < 2; ++kb) {
      const unsigned int wA0 = cvtpk(s[8 * kb + 0], s[8 * kb + 1]);
      const unsigned int wA1 = cvtpk(s[8 * kb + 2], s[8 * kb + 3]);
      const unsigned int wB0 = cvtpk(s[8 * kb + 4], s[8 * kb + 5]);
      const unsigned int wB1 = cvtpk(s[8 * kb + 6], s[8 * kb + 7]);
      const u32x2 p02 = __builtin_amdgcn_permlane32_swap(wA0, wB0, false, false);
      const u32x2 p13 = __builtin_amdgcn_permlane32_swap(wA1, wB1, false, false);
      u32x4 pw;
      pw[0] = p02[0];
      pw[1] = p13[0];
      pw[2] = p02[1];
      pw[3] = p13[1];
      const bf16x8 pfrag = __builtin_bit_cast(bf16x8, pw);
      __builtin_amdgcn_s_setprio(1);
      acc0 = __builtin_amdgcn_mfma_f32_32x32x16_bf16(kb ? va10 : va00, pfrag, acc0, 0, 0, 0);
      acc1 = __builtin_amdgcn_mfma_f32_32x32x16_bf16(kb ? va11 : va01, pfrag, acc1, 0, 0, 0);
      __builtin_amdgcn_s_setprio(0);
    }

    // T14: write staged regs to the other buffer (vmcnt wait lands here)
    if (kt < 31) {
      char* Ktn = pool + (cur ^ 1) * 16384;
      char* Vtn = pool + 32768 + (cur ^ 1) * 16384;
      *reinterpret_cast<uint4*>(Ktn + kd0) = rk0;
      *reinterpret_cast<uint4*>(Ktn + kd1) = rk1;
      *reinterpret_cast<uint4*>(Vtn + vd0) = rv0;
      *reinterpret_cast<uint4*>(Vtn + vd1) = rv1;
      mw = mw_n;
    }
    __syncthreads();
  }

  // ---- 4-way merge through LDS (aliases staging pool; loop's last barrier guards)
  float* MAcc = reinterpret_cast<float*>(pool);            // [2][3][32][66]
  float* Mml = reinterpret_cast<float*>(pool + 50688);     // [2][3][2][64]
  if (wk > 0) {
    float* A = MAcc + (size_t)(wq * 3 + (wk - 1)) * 32 * 66;
#pragma unroll
    for (int r = 0; r < 16; ++r) {
      A[r * 66 + l] = acc0[r];
      A[(16 + r) * 66 + l] = acc1[r];
    }
    float* Mm = Mml + (wq * 3 + (wk - 1)) * 128;
    Mm[l] = m_r;
    Mm[64 + l] = l_r;
  }
  __syncthreads();
  if (wk == 0) {
    float M = m_r;
#pragma unroll
    for (int s0 = 0; s0 < 3; ++s0) M = fmaxf(M, Mml[(wq * 3 + s0) * 128 + l]);
    const float c_self = exp2f(m_r - M);
    float cs[3];
    float L = l_r * c_self;
#pragma unroll
    for (int s0 = 0; s0 < 3; ++s0) {
      cs[s0] = exp2f(Mml[(wq * 3 + s0) * 128 + l] - M);
      L += Mml[(wq * 3 + s0) * 128 + 64 + l] * cs[s0];
    }
    const float inv = 1.0f / L;
    float* ob = Out + (size_t)b * EH * NS + qrow;
#pragma unroll
    for (int r = 0; r < 16; ++r) {
      const int v0 = (r & 3) + ((r >> 2) << 3) + (hi << 2);
      float o0 = acc0[r] * c_self;
      float o1 = acc1[r] * c_self;
#pragma unroll
      for (int s0 = 0; s0 < 3; ++s0) {
        const float* A = MAcc + (size_t)(wq * 3 + s0) * 32 * 66;
        o0 += A[r * 66 + l] * cs[s0];
        o1 += A[(16 + r) * 66 + l] * cs[s0];
      }
      ob[(size_t)v0 * NS] = o0 * inv;
      ob[(size_t)(v0 + 32) * NS] = o1 * inv;
    }
  }
}

extern "C" void kernel_launch(void* const* d_in, const int* in_sizes, int n_in,
                              void* d_out, int out_size, void* d_ws, size_t ws_size,
                              hipStream_t stream) {
  const float* Qf = (const float*)d_in[0];
  const float* Kf = (const float*)d_in[1];
  const float* Vf = (const float*)d_in[2];
  const unsigned char* Mp = (const unsigned char*)d_in[3];
  float* Out = (float*)d_out;

  unsigned short* Kb = (unsigned short*)d_ws;                       // 4 MB
  unsigned short* Vb = Kb + (size_t)NB * NS * EH;                   // 4 MB
  unsigned int* Bits = (unsigned int*)(Vb + (size_t)NB * NS * EH);  // 2 MB
  int* mflag = (int*)(Bits + (size_t)NS * (NS / 32));

  k_detect_mask<<<1, 64, 0, stream>>>((const unsigned int*)Mp, mflag);
  k_mask_bits<<<dim3(64, 64), 256, 0, stream>>>(Mp, mflag, Bits);
  k_prep<<<dim3(64, 8, 2), 256, 0, stream>>>(Kf, Vf, Kb, Vb);
  k_attn4<<<dim3(512), 512, 0, stream>>>(Kb, Vb, Qf, Bits, Out);
}